// Round 1
// baseline (469.804 us; speedup 1.0000x reference)
//
#include <hip/hip_runtime.h>

#define GG 256   // NUM_GRAPHS
#define ZZDIM 32 // Z
#define KK 64    // K
#define EMBD 10  // EMB

// ---------------- kernels ----------------

// deg[i] = 2.0 (improved self-loop fill), gsum = 0
__global__ void init_kernel(float* __restrict__ deg, float* __restrict__ gsum, int n) {
    int i = blockIdx.x * blockDim.x + threadIdx.x;
    if (i < n) deg[i] = 2.0f;
    if (i < GG * ZZDIM) gsum[i] = 0.0f;
}

// deg[col[e]] += w[e]
__global__ void deg_kernel(const int* __restrict__ col, const float* __restrict__ w,
                           float* __restrict__ deg, int e) {
    int i = blockIdx.x * blockDim.x + threadIdx.x;
    if (i < e) atomicAdd(&deg[col[i]], w[i]);
}

// hs[i,z] = rsqrt(deg[i]) * sum_j embed[x[i],j] * Wc[j,z];  dinv[i] = rsqrt(deg[i])
__global__ void hs_kernel(const int* __restrict__ x, const float* __restrict__ emb,
                          const float* __restrict__ Wc, const float* __restrict__ deg,
                          float* __restrict__ dinv, float* __restrict__ hs, int n) {
    int tid = blockIdx.x * blockDim.x + threadIdx.x;
    int i = tid >> 5, z = tid & 31;
    if (i >= n) return;
    float d = rsqrtf(deg[i]);            // deg >= 2 always (weights >= 0, self-loop 2.0)
    if (z == 0) dinv[i] = d;
    int xi = x[i];
    const float* er = emb + (long)xi * EMBD;
    float acc = 0.f;
#pragma unroll
    for (int j = 0; j < EMBD; ++j) acc += er[j] * Wc[j * ZZDIM + z];
    hs[(long)i * ZZDIM + z] = d * acc;
}

// per-edge (32 lanes = 32 channels): LDS-accumulate w*dinv[col]*hs[row] into graph row,
// plus self-loop items 2*dinv[i]*hs[i]; flush block-local sums with one atomic each.
__global__ void __launch_bounds__(256) scatter_kernel(
    const int* __restrict__ ei, const float* __restrict__ w,
    const int* __restrict__ batch, const float* __restrict__ dinv,
    const float* __restrict__ hs, float* __restrict__ gsum, int e, int n) {
    __shared__ float s[GG * 33];  // +1 pad: bank = (g+z)%32, conflict-free per edge
    for (int i = threadIdx.x; i < GG * 33; i += 256) s[i] = 0.f;
    __syncthreads();

    const int z = threadIdx.x & 31;
    const int total = e + n;
    const int gpb = 256 >> 5;  // 8 item-groups per block
    int it = blockIdx.x * gpb + (threadIdx.x >> 5);
    const int stride = gridDim.x * gpb;
    for (; it < total; it += stride) {
        float c; int g;
        if (it < e) {
            int row = ei[it];
            int col = ei[e + it];
            g = batch[col];
            c = w[it] * dinv[col] * hs[(long)row * ZZDIM + z];
        } else {
            int i = it - e;
            g = batch[i];
            c = 2.0f * dinv[i] * hs[(long)i * ZZDIM + z];
        }
        atomicAdd(&s[g * 33 + z], c);
    }
    __syncthreads();
    for (int idx = threadIdx.x; idx < GG * ZZDIM; idx += 256) {
        float v = s[(idx >> 5) * 33 + (idx & 31)];
        if (v != 0.0f) atomicAdd(&gsum[idx], v);
    }
}

// counts via binary search on sorted batch (no atomics)
__global__ void cnt_kernel(const int* __restrict__ batch, float* __restrict__ cnt, int n) {
    __shared__ int lb[GG + 1];
    int g = threadIdx.x;  // 256 threads
    int lo = 0, hi = n;
    while (lo < hi) {  // first index with batch[i] >= g
        int mid = (lo + hi) >> 1;
        if (batch[mid] < g) lo = mid + 1; else hi = mid;
    }
    lb[g] = lo;
    if (g == 0) lb[GG] = n;
    __syncthreads();
    cnt[g] = (float)(lb[g + 1] - lb[g]);
}

// pooled[g,z] = b[z] + gsum[g,z]/cnt[g] (0 if empty graph); logits = pooled @ Wr
__global__ void finalize_kernel(const float* __restrict__ gsum, const float* __restrict__ cnt,
                                const float* __restrict__ bc, const float* __restrict__ Wr,
                                float* __restrict__ out) {
    int g = blockIdx.x;
    int k = threadIdx.x;  // 64 threads
    __shared__ float p[ZZDIM];
    float c = cnt[g];
    if (k < ZZDIM) {
        float v = (c > 0.f) ? (bc[k] + gsum[g * ZZDIM + k] / c) : 0.f;
        out[g * ZZDIM + k] = v;
        p[k] = v;
    }
    __syncthreads();
    float acc = 0.f;
#pragma unroll
    for (int zz = 0; zz < ZZDIM; ++zz) acc += p[zz] * Wr[zz * KK + k];
    out[GG * ZZDIM + g * KK + k] = acc;
}

// ---------------- launch ----------------

extern "C" void kernel_launch(void* const* d_in, const int* in_sizes, int n_in,
                              void* d_out, int out_size, void* d_ws, size_t ws_size,
                              hipStream_t stream) {
    const int*   x     = (const int*)d_in[0];
    const int*   ei    = (const int*)d_in[1];   // [2,E]: rows then cols
    const float* ew    = (const float*)d_in[2];
    const int*   batch = (const int*)d_in[3];
    const float* emb   = (const float*)d_in[4];
    const float* Wc    = (const float*)d_in[5];
    const float* bc    = (const float*)d_in[6];
    const float* Wr    = (const float*)d_in[7];
    float* out = (float*)d_out;

    const int n = in_sizes[0];
    const int e = in_sizes[2];

    float* ws   = (float*)d_ws;
    float* deg  = ws;                    // n
    float* dinv = ws + n;                // n
    float* hs   = ws + 2L * n;           // n*32
    float* gsum = ws + 34L * n;          // 256*32
    float* cnt  = gsum + GG * ZZDIM;     // 256

    init_kernel<<<(n + 255) / 256, 256, 0, stream>>>(deg, gsum, n);
    deg_kernel<<<(e + 255) / 256, 256, 0, stream>>>(ei + e, ew, deg, e);
    hs_kernel<<<(n * 32 + 255) / 256, 256, 0, stream>>>(x, emb, Wc, deg, dinv, hs, n);
    cnt_kernel<<<1, 256, 0, stream>>>(batch, cnt, n);
    scatter_kernel<<<1024, 256, 0, stream>>>(ei, ew, batch, dinv, hs, gsum, e, n);
    finalize_kernel<<<GG, KK, 0, stream>>>(gsum, cnt, bc, Wr, out);
}

// Round 2
// 424.428 us; speedup vs baseline: 1.1069x; 1.1069x over previous
//
#include <hip/hip_runtime.h>
#include <hip/hip_fp16.h>

#define GG 256   // NUM_GRAPHS
#define ZZDIM 32 // Z
#define KK 64    // K
#define EMBD 10  // EMB

// ---------------- kernels ----------------

// deg[i] = 2.0 (improved self-loop fill), gsum = 0
__global__ void init_kernel(float* __restrict__ deg, float* __restrict__ gsum, int n) {
    int i = blockIdx.x * blockDim.x + threadIdx.x;
    if (i < n) deg[i] = 2.0f;
    if (i < GG * ZZDIM) gsum[i] = 0.0f;
}

// deg[col[e]] += w[e]   (random atomics into 0.4 MB, L2-resident)
__global__ void deg_kernel(const int* __restrict__ col, const float* __restrict__ w,
                           float* __restrict__ deg, int e) {
    int i = blockIdx.x * blockDim.x + threadIdx.x;
    if (i < e) atomicAdd(&deg[col[i]], w[i]);
}

// hs[i,z] = rsqrt(deg[i]) * sum_j embed[x[i],j] * Wc[j,z];  dinv[i] = rsqrt(deg[i])
__global__ void hs_kernel(const int* __restrict__ x, const float* __restrict__ emb,
                          const float* __restrict__ Wc, const float* __restrict__ deg,
                          float* __restrict__ dinv, float* __restrict__ hs, int n) {
    int tid = blockIdx.x * blockDim.x + threadIdx.x;
    int i = tid >> 5, z = tid & 31;
    if (i >= n) return;
    float d = rsqrtf(deg[i]);            // deg >= 2 always (weights >= 0, self-loop 2.0)
    if (z == 0) dinv[i] = d;
    int xi = x[i];
    const float* er = emb + (long)xi * EMBD;
    float acc = 0.f;
#pragma unroll
    for (int j = 0; j < EMBD; ++j) acc += er[j] * Wc[j * ZZDIM + z];
    hs[(long)i * ZZDIM + z] = d * acc;
}

// pk[e] = (batch[col] << 16) | fp16(w * dinv[col])  — streaming + small L2 gathers
__global__ void prep_kernel(const int* __restrict__ col, const float* __restrict__ w,
                            const int* __restrict__ batch, const float* __restrict__ dinv,
                            unsigned int* __restrict__ pk, int e) {
    int i = blockIdx.x * blockDim.x + threadIdx.x;
    if (i >= e) return;
    int c = col[i];
    float cf = w[i] * dinv[c];
    unsigned int g = (unsigned int)batch[c];
    pk[i] = (g << 16) | (unsigned int)__half_as_ushort(__float2half_rn(cf));
}

// 32 lanes per item, 4 items per group-iteration: 4 independent hs gathers in flight.
// LDS [256][32] unpadded: within a group z spans all banks; cross-group = 2-way (free).
__global__ void __launch_bounds__(256) scatter_kernel(
    const int* __restrict__ row, const unsigned int* __restrict__ pk,
    const int* __restrict__ batch, const float* __restrict__ dinv,
    const float* __restrict__ hs, float* __restrict__ gsum, int e, int n) {
    __shared__ float s[GG * ZZDIM];
    for (int i = threadIdx.x; i < GG * ZZDIM; i += 256) s[i] = 0.f;
    __syncthreads();

    const int z = threadIdx.x & 31;
    const long grp = blockIdx.x * 8L + (threadIdx.x >> 5);  // 8 groups/block
    const long stride = gridDim.x * 8L * 4L;

    // edges (e % 4 == 0; base 16B-aligned)
    for (long it = grp * 4; it + 3 < e; it += stride) {
        int4 r4 = *(const int4*)(row + it);
        uint4 p4 = *(const uint4*)(pk + it);
        float v0 = hs[(long)r4.x * ZZDIM + z];
        float v1 = hs[(long)r4.y * ZZDIM + z];
        float v2 = hs[(long)r4.z * ZZDIM + z];
        float v3 = hs[(long)r4.w * ZZDIM + z];
        atomicAdd(&s[(p4.x >> 16) * ZZDIM + z],
                  __half2float(__ushort_as_half((unsigned short)(p4.x & 0xffffu))) * v0);
        atomicAdd(&s[(p4.y >> 16) * ZZDIM + z],
                  __half2float(__ushort_as_half((unsigned short)(p4.y & 0xffffu))) * v1);
        atomicAdd(&s[(p4.z >> 16) * ZZDIM + z],
                  __half2float(__ushort_as_half((unsigned short)(p4.z & 0xffffu))) * v2);
        atomicAdd(&s[(p4.w >> 16) * ZZDIM + z],
                  __half2float(__ushort_as_half((unsigned short)(p4.w & 0xffffu))) * v3);
    }

    // self-loops: 2*dinv[i]*hs[i] into batch[i]  (n % 4 == 0; coalesced reads)
    for (long i = grp * 4; i + 3 < n; i += stride) {
        int4 b4 = *(const int4*)(batch + i);
        float4 dv = *(const float4*)(dinv + i);
        float v0 = hs[(i + 0) * ZZDIM + z];
        float v1 = hs[(i + 1) * ZZDIM + z];
        float v2 = hs[(i + 2) * ZZDIM + z];
        float v3 = hs[(i + 3) * ZZDIM + z];
        atomicAdd(&s[b4.x * ZZDIM + z], 2.0f * dv.x * v0);
        atomicAdd(&s[b4.y * ZZDIM + z], 2.0f * dv.y * v1);
        atomicAdd(&s[b4.z * ZZDIM + z], 2.0f * dv.z * v2);
        atomicAdd(&s[b4.w * ZZDIM + z], 2.0f * dv.w * v3);
    }

    __syncthreads();
    for (int idx = threadIdx.x; idx < GG * ZZDIM; idx += 256)
        atomicAdd(&gsum[idx], s[idx]);
}

// counts via binary search on sorted batch (no atomics)
__global__ void cnt_kernel(const int* __restrict__ batch, float* __restrict__ cnt, int n) {
    __shared__ int lb[GG + 1];
    int g = threadIdx.x;  // 256 threads
    int lo = 0, hi = n;
    while (lo < hi) {  // first index with batch[i] >= g
        int mid = (lo + hi) >> 1;
        if (batch[mid] < g) lo = mid + 1; else hi = mid;
    }
    lb[g] = lo;
    if (g == 0) lb[GG] = n;
    __syncthreads();
    cnt[g] = (float)(lb[g + 1] - lb[g]);
}

// pooled[g,z] = b[z] + gsum[g,z]/cnt[g] (0 if empty graph); logits = pooled @ Wr
__global__ void finalize_kernel(const float* __restrict__ gsum, const float* __restrict__ cnt,
                                const float* __restrict__ bc, const float* __restrict__ Wr,
                                float* __restrict__ out) {
    int g = blockIdx.x;
    int k = threadIdx.x;  // 64 threads
    __shared__ float p[ZZDIM];
    float c = cnt[g];
    if (k < ZZDIM) {
        float v = (c > 0.f) ? (bc[k] + gsum[g * ZZDIM + k] / c) : 0.f;
        out[g * ZZDIM + k] = v;
        p[k] = v;
    }
    __syncthreads();
    float acc = 0.f;
#pragma unroll
    for (int zz = 0; zz < ZZDIM; ++zz) acc += p[zz] * Wr[zz * KK + k];
    out[GG * ZZDIM + g * KK + k] = acc;
}

// ---------------- launch ----------------

extern "C" void kernel_launch(void* const* d_in, const int* in_sizes, int n_in,
                              void* d_out, int out_size, void* d_ws, size_t ws_size,
                              hipStream_t stream) {
    const int*   x     = (const int*)d_in[0];
    const int*   ei    = (const int*)d_in[1];   // [2,E]: rows then cols
    const float* ew    = (const float*)d_in[2];
    const int*   batch = (const int*)d_in[3];
    const float* emb   = (const float*)d_in[4];
    const float* Wc    = (const float*)d_in[5];
    const float* bc    = (const float*)d_in[6];
    const float* Wr    = (const float*)d_in[7];
    float* out = (float*)d_out;

    const int n = in_sizes[0];
    const int e = in_sizes[2];

    float* ws   = (float*)d_ws;
    float* deg  = ws;                    // n
    float* dinv = ws + n;                // n
    float* hs   = ws + 2L * n;           // n*32
    float* gsum = ws + 34L * n;          // 256*32
    float* cnt  = gsum + GG * ZZDIM;     // 256
    unsigned int* pk = (unsigned int*)(cnt + GG);  // e

    init_kernel<<<(n + 255) / 256, 256, 0, stream>>>(deg, gsum, n);
    deg_kernel<<<(e + 255) / 256, 256, 0, stream>>>(ei + e, ew, deg, e);
    hs_kernel<<<(n * 32 + 255) / 256, 256, 0, stream>>>(x, emb, Wc, deg, dinv, hs, n);
    prep_kernel<<<(e + 255) / 256, 256, 0, stream>>>(ei + e, ew, batch, dinv, pk, e);
    cnt_kernel<<<1, 256, 0, stream>>>(batch, cnt, n);
    scatter_kernel<<<1280, 256, 0, stream>>>(ei, pk, batch, dinv, hs, gsum, e, n);
    finalize_kernel<<<GG, KK, 0, stream>>>(gsum, cnt, bc, Wr, out);
}

// Round 3
// 409.785 us; speedup vs baseline: 1.1465x; 1.0357x over previous
//
#include <hip/hip_runtime.h>
#include <hip/hip_fp16.h>

#define GG 256   // NUM_GRAPHS
#define ZZDIM 32 // Z
#define KK 64    // K
#define EMBD 10  // EMB
#define NREP 64  // replica accumulators (contention divider)

// ---------------- kernels ----------------

// deg[i] = 2.0 (improved self-loop fill); zero the replica accumulators
__global__ void init_kernel(float* __restrict__ deg, float* __restrict__ rep, int n) {
    int i = blockIdx.x * blockDim.x + threadIdx.x;
    if (i < n) deg[i] = 2.0f;
    if (i < NREP * GG * ZZDIM) rep[i] = 0.0f;
}

// deg[col[e]] += w[e]   (random atomics into 0.4 MB, L2-resident, low per-line contention)
__global__ void deg_kernel(const int* __restrict__ col, const float* __restrict__ w,
                           float* __restrict__ deg, int e) {
    int i = blockIdx.x * blockDim.x + threadIdx.x;
    if (i < e) atomicAdd(&deg[col[i]], w[i]);
}

// hs[i,z] = rsqrt(deg[i]) * sum_j embed[x[i],j] * Wc[j,z];  dinv[i] = rsqrt(deg[i])
__global__ void hs_kernel(const int* __restrict__ x, const float* __restrict__ emb,
                          const float* __restrict__ Wc, const float* __restrict__ deg,
                          float* __restrict__ dinv, float* __restrict__ hs, int n) {
    int tid = blockIdx.x * blockDim.x + threadIdx.x;
    int i = tid >> 5, z = tid & 31;
    if (i >= n) return;
    float d = rsqrtf(deg[i]);            // deg >= 2 always (weights >= 0, self-loop 2.0)
    if (z == 0) dinv[i] = d;
    int xi = x[i];
    const float* er = emb + (long)xi * EMBD;
    float acc = 0.f;
#pragma unroll
    for (int j = 0; j < EMBD; ++j) acc += er[j] * Wc[j * ZZDIM + z];
    hs[(long)i * ZZDIM + z] = d * acc;
}

// pk[e] = (batch[col] << 16) | fp16(w * dinv[col])  — streaming + small L2 gathers
__global__ void prep_kernel(const int* __restrict__ col, const float* __restrict__ w,
                            const int* __restrict__ batch, const float* __restrict__ dinv,
                            unsigned int* __restrict__ pk, int e) {
    int i = blockIdx.x * blockDim.x + threadIdx.x;
    if (i >= e) return;
    int c = col[i];
    float cf = w[i] * dinv[c];
    unsigned int g = (unsigned int)batch[c];
    pk[i] = (g << 16) | (unsigned int)__half_as_ushort(__float2half_rn(cf));
}

// 32 lanes per item, 8 items per group-iteration: 8 independent hs gathers in flight.
// LDS [256][32] unpadded: within a group z spans all banks; cross-group = 2-way (free).
// Flush into one of NREP replica accumulators -> per-line atomic serialization /20.
__global__ void __launch_bounds__(256) scatter_kernel(
    const int* __restrict__ row, const unsigned int* __restrict__ pk,
    const int* __restrict__ batch, const float* __restrict__ dinv,
    const float* __restrict__ hs, float* __restrict__ rep, int e, int n) {
    __shared__ float s[GG * ZZDIM];
    for (int i = threadIdx.x; i < GG * ZZDIM; i += 256) s[i] = 0.f;
    __syncthreads();

    const int z = threadIdx.x & 31;
    const long grp = blockIdx.x * 8L + (threadIdx.x >> 5);  // 8 groups/block

    // edges: 8 items per iteration (e % 8 == 0)
    const long estride = gridDim.x * 8L * 8L;
    for (long it = grp * 8; it + 7 < e; it += estride) {
        int4 ra = *(const int4*)(row + it);
        int4 rb = *(const int4*)(row + it + 4);
        uint4 pa = *(const uint4*)(pk + it);
        uint4 pb = *(const uint4*)(pk + it + 4);
        float v0 = hs[(long)ra.x * ZZDIM + z];
        float v1 = hs[(long)ra.y * ZZDIM + z];
        float v2 = hs[(long)ra.z * ZZDIM + z];
        float v3 = hs[(long)ra.w * ZZDIM + z];
        float v4 = hs[(long)rb.x * ZZDIM + z];
        float v5 = hs[(long)rb.y * ZZDIM + z];
        float v6 = hs[(long)rb.z * ZZDIM + z];
        float v7 = hs[(long)rb.w * ZZDIM + z];
        atomicAdd(&s[(pa.x >> 16) * ZZDIM + z],
                  __half2float(__ushort_as_half((unsigned short)(pa.x & 0xffffu))) * v0);
        atomicAdd(&s[(pa.y >> 16) * ZZDIM + z],
                  __half2float(__ushort_as_half((unsigned short)(pa.y & 0xffffu))) * v1);
        atomicAdd(&s[(pa.z >> 16) * ZZDIM + z],
                  __half2float(__ushort_as_half((unsigned short)(pa.z & 0xffffu))) * v2);
        atomicAdd(&s[(pa.w >> 16) * ZZDIM + z],
                  __half2float(__ushort_as_half((unsigned short)(pa.w & 0xffffu))) * v3);
        atomicAdd(&s[(pb.x >> 16) * ZZDIM + z],
                  __half2float(__ushort_as_half((unsigned short)(pb.x & 0xffffu))) * v4);
        atomicAdd(&s[(pb.y >> 16) * ZZDIM + z],
                  __half2float(__ushort_as_half((unsigned short)(pb.y & 0xffffu))) * v5);
        atomicAdd(&s[(pb.z >> 16) * ZZDIM + z],
                  __half2float(__ushort_as_half((unsigned short)(pb.z & 0xffffu))) * v6);
        atomicAdd(&s[(pb.w >> 16) * ZZDIM + z],
                  __half2float(__ushort_as_half((unsigned short)(pb.w & 0xffffu))) * v7);
    }

    // self-loops: 2*dinv[i]*hs[i] into batch[i]  (n % 4 == 0; coalesced reads)
    const long sstride = gridDim.x * 8L * 4L;
    for (long i = grp * 4; i + 3 < n; i += sstride) {
        int4 b4 = *(const int4*)(batch + i);
        float4 dv = *(const float4*)(dinv + i);
        float v0 = hs[(i + 0) * ZZDIM + z];
        float v1 = hs[(i + 1) * ZZDIM + z];
        float v2 = hs[(i + 2) * ZZDIM + z];
        float v3 = hs[(i + 3) * ZZDIM + z];
        atomicAdd(&s[b4.x * ZZDIM + z], 2.0f * dv.x * v0);
        atomicAdd(&s[b4.y * ZZDIM + z], 2.0f * dv.y * v1);
        atomicAdd(&s[b4.z * ZZDIM + z], 2.0f * dv.z * v2);
        atomicAdd(&s[b4.w * ZZDIM + z], 2.0f * dv.w * v3);
    }

    __syncthreads();
    float* r0 = rep + (long)(blockIdx.x & (NREP - 1)) * (GG * ZZDIM);
    for (int idx = threadIdx.x; idx < GG * ZZDIM; idx += 256)
        atomicAdd(&r0[idx], s[idx]);
}

// counts via binary search on sorted batch (no atomics)
__global__ void cnt_kernel(const int* __restrict__ batch, float* __restrict__ cnt, int n) {
    __shared__ int lb[GG + 1];
    int g = threadIdx.x;  // 256 threads
    int lo = 0, hi = n;
    while (lo < hi) {  // first index with batch[i] >= g
        int mid = (lo + hi) >> 1;
        if (batch[mid] < g) lo = mid + 1; else hi = mid;
    }
    lb[g] = lo;
    if (g == 0) lb[GG] = n;
    __syncthreads();
    cnt[g] = (float)(lb[g + 1] - lb[g]);
}

// pooled[g,z] = b[z] + (sum_r rep[r][g,z])/cnt[g] (0 if empty); logits = pooled @ Wr
__global__ void finalize_kernel(const float* __restrict__ rep, const float* __restrict__ cnt,
                                const float* __restrict__ bc, const float* __restrict__ Wr,
                                float* __restrict__ out) {
    int g = blockIdx.x;
    int k = threadIdx.x;  // 64 threads
    __shared__ float p[ZZDIM];
    if (k < ZZDIM) {
        float acc = 0.f;
#pragma unroll 8
        for (int r = 0; r < NREP; ++r) acc += rep[(long)r * (GG * ZZDIM) + g * ZZDIM + k];
        float c = cnt[g];
        float v = (c > 0.f) ? (bc[k] + acc / c) : 0.f;
        out[g * ZZDIM + k] = v;
        p[k] = v;
    }
    __syncthreads();
    float acc = 0.f;
#pragma unroll
    for (int zz = 0; zz < ZZDIM; ++zz) acc += p[zz] * Wr[zz * KK + k];
    out[GG * ZZDIM + g * KK + k] = acc;
}

// ---------------- launch ----------------

extern "C" void kernel_launch(void* const* d_in, const int* in_sizes, int n_in,
                              void* d_out, int out_size, void* d_ws, size_t ws_size,
                              hipStream_t stream) {
    const int*   x     = (const int*)d_in[0];
    const int*   ei    = (const int*)d_in[1];   // [2,E]: rows then cols
    const float* ew    = (const float*)d_in[2];
    const int*   batch = (const int*)d_in[3];
    const float* emb   = (const float*)d_in[4];
    const float* Wc    = (const float*)d_in[5];
    const float* bc    = (const float*)d_in[6];
    const float* Wr    = (const float*)d_in[7];
    float* out = (float*)d_out;

    const int n = in_sizes[0];
    const int e = in_sizes[2];

    float* ws   = (float*)d_ws;
    float* deg  = ws;                        // n
    float* dinv = ws + n;                    // n
    float* hs   = ws + 2L * n;               // n*32
    float* rep  = ws + 34L * n;              // NREP*256*32
    float* cnt  = rep + NREP * GG * ZZDIM;   // 256
    unsigned int* pk = (unsigned int*)(cnt + GG);  // e

    const int zinit = NREP * GG * ZZDIM;     // 524288
    const int initN = (n > zinit ? n : zinit);

    init_kernel<<<(initN + 255) / 256, 256, 0, stream>>>(deg, rep, n);
    deg_kernel<<<(e + 255) / 256, 256, 0, stream>>>(ei + e, ew, deg, e);
    hs_kernel<<<(n * 32 + 255) / 256, 256, 0, stream>>>(x, emb, Wc, deg, dinv, hs, n);
    prep_kernel<<<(e + 255) / 256, 256, 0, stream>>>(ei + e, ew, batch, dinv, pk, e);
    cnt_kernel<<<1, 256, 0, stream>>>(batch, cnt, n);
    scatter_kernel<<<1280, 256, 0, stream>>>(ei, pk, batch, dinv, hs, rep, e, n);
    finalize_kernel<<<GG, KK, 0, stream>>>(rep, cnt, bc, Wr, out);
}